// Round 5
// baseline (120.336 us; speedup 1.0000x reference)
//
#include <hip/hip_runtime.h>
#include <hip/hip_bf16.h>

// Word2Vec fused loss. M=4086 centers (pad 4096), V=32000, D=128.
// exp2/log2 domain: A holds bf16(ctx_mean*log2e); per-row S = sum_v 2^(A.Wb_v);
// loss = sum_i [ LN2*log2(S_i) - tgt_i ].
//
// k_gemm R5: fat waves. Block = 256 M-rows x 4 waves (64 rows/wave, a[4][4]
// pinned in VGPRs via asm keep-alive to defeat the R2 remat). Halves LDS-read
// volume vs R4 (each B-tile read by 4 waves instead of 8 per 256 M-rows).
// B staged 32 rows/step into LDS dbuf via global_load_lds (width 16),
// XOR-swizzled in Wb so ds_read_b128 of B-frags is conflict-free.
// grid (16, 40): 640 blocks, all co-resident at 3 blocks/CU.

#define NCTR 4086
#define WIN 5
#define VOC 32000
#define DIM 128
#define MPAD 4096
#define LOG2E 1.44269504088896340736f
#define LN2 0.69314718055994530942f

#define MT 256
#define NT 32
#define SSTR 40
#define TSTEP 25

typedef __attribute__((ext_vector_type(8))) __bf16 bf16x8;
typedef __attribute__((ext_vector_type(4))) __bf16 bf16x4;
typedef __attribute__((ext_vector_type(4))) float f32x4;

// ws layout (bytes):
//   [0,        8192000)  Wb : bf16 VOC*DIM, XOR-swizzled chunks within each row
//   [8192000,  9240576)  A  : bf16 MPAD*DIM plain row-major (log2e-scaled)
//   [9240576,  9256960)  expsum : float MPAD
//   [9256960,  9273344)  tgt    : float MPAD
#define WS_A      8192000
#define WS_EXPSUM 9240576
#define WS_TGT    9256960

#define NWCONV 2000   // VOC*16 chunk-units / 256
#define NCTXB  512    // MPAD/8 (8 rows per 256-thread block)

#if __has_builtin(__builtin_amdgcn_exp2f)
#define EXP2(x) __builtin_amdgcn_exp2f(x)
#else
#define EXP2(x) exp2f(x)
#endif

#define GLOAD16(g, l) __builtin_amdgcn_global_load_lds(                         \
    (const __attribute__((address_space(1))) void*)(g),                         \
    (__attribute__((address_space(3))) void*)(l), 16, 0, 0)

__global__ __launch_bounds__(256) void k_setup(const int* __restrict__ tokens,
                                               const float* __restrict__ emb,
                                               const float* __restrict__ W,
                                               __bf16* __restrict__ Wb,
                                               __bf16* __restrict__ A,
                                               float* __restrict__ tgt,
                                               float* __restrict__ expsum) {
    if (blockIdx.x < NWCONV) {
        // W fp32 -> Wb bf16, one 16-B chunk per thread, XOR-swizzled:
        // chunk c of row r lands at chunk position c ^ (r & 7).
        int id = blockIdx.x * 256 + threadIdx.x;   // (r, c) unit
        int r = id >> 4, c = id & 15;
        const f32x4* src = (const f32x4*)(W + (size_t)r * DIM + c * 8);
        f32x4 v0 = src[0], v1 = src[1];
        bf16x8 o;
        o[0] = (__bf16)v0.x; o[1] = (__bf16)v0.y; o[2] = (__bf16)v0.z; o[3] = (__bf16)v0.w;
        o[4] = (__bf16)v1.x; o[5] = (__bf16)v1.y; o[6] = (__bf16)v1.z; o[7] = (__bf16)v1.w;
        ((bf16x8*)Wb)[r * 16 + (c ^ (r & 7))] = o;
        return;
    }
    // ctx part: 8 rows per block; 32 lanes per row, 4 dims per lane (f32x4)
    int bid = blockIdx.x - NWCONV;
    int r = threadIdx.x >> 5;
    int c = threadIdx.x & 31;
    int i = bid * 8 + r;
    if (c == 0) expsum[i] = 0.0f;
    if (i >= NCTR) {
        bf16x4 zb; zb[0] = zb[1] = zb[2] = zb[3] = (__bf16)0.0f;
        ((bf16x4*)A)[i * 32 + c] = zb;
        if (c == 0) tgt[i] = 0.0f;
        return;
    }
    int p = i + WIN;
    const f32x4* emb4 = (const f32x4*)emb;
    f32x4 s = {0.0f, 0.0f, 0.0f, 0.0f};
#pragma unroll
    for (int o = 1; o <= WIN; ++o) {
        s += emb4[(size_t)tokens[p - o] * 32 + c];
        s += emb4[(size_t)tokens[p + o] * 32 + c];
    }
    f32x4 m = s * 0.1f;
    bf16x4 ab;
#pragma unroll
    for (int j = 0; j < 4; ++j) ab[j] = (__bf16)(m[j] * LOG2E);
    ((bf16x4*)A)[i * 32 + c] = ab;
    // target logit (natural-log domain, fp32)
    f32x4 w = ((const f32x4*)W)[(size_t)tokens[p] * 32 + c];
    float prod = m.x * w.x + m.y * w.y + m.z * w.z + m.w * w.w;
#pragma unroll
    for (int k = 1; k <= 16; k <<= 1) prod += __shfl_xor(prod, k);
    if (c == 0) tgt[i] = prod;
}

// grid (16, 40): blockIdx.x = M-tile (256 rows), blockIdx.y = N-stream.
__global__ __launch_bounds__(256, 3) void k_gemm(const __bf16* __restrict__ A,
                                                 const __bf16* __restrict__ Wb,
                                                 float* __restrict__ expsum) {
    __shared__ __align__(16) __bf16 lds[2][NT * DIM];   // 2 x 8 KB
    const int tid  = threadIdx.x;
    const int lane = tid & 63;
    const int wv   = tid >> 6;
    const int lrow = lane & 15;
    const int quad = lane >> 4;
    const int m0   = blockIdx.x * MT;
    const int sid  = blockIdx.y;

    // A-frags: rows m0 + wv*64 + ms*16 + lrow, chunk kb*4+quad (plain layout).
    // Pinned with asm keep-alive: R2 showed the compiler remats these global
    // loads into the loop at low VGPR targets, serializing the K-stream.
    bf16x8 a[4][4];
    {
        const bf16x8* Ap = (const bf16x8*)A + (size_t)(m0 + wv * 64 + lrow) * 16 + quad;
#pragma unroll
        for (int ms = 0; ms < 4; ++ms)
#pragma unroll
            for (int kb = 0; kb < 4; ++kb) {
                f32x4 t = __builtin_bit_cast(f32x4, Ap[ms * 256 + kb * 4]);
                asm volatile("" : "+v"(t));
                a[ms][kb] = __builtin_bit_cast(bf16x8, t);
            }
    }

    float run[4][4];
#pragma unroll
    for (int ms = 0; ms < 4; ++ms)
#pragma unroll
        for (int r = 0; r < 4; ++r) run[ms][r] = 0.0f;

    // staging: step t covers Wb rows (t*SSTR + sid)*NT .. +NT (8 KB, swizzled
    // in Wb). Wave wv stages its contiguous 2-KB slice with two width-16
    // global_load_lds (deposit = base + lane*16 each).
    const __bf16* gbase = Wb + (size_t)sid * NT * DIM + (size_t)wv * 1024 + (size_t)lane * 8;
    const int gstep = SSTR * NT * DIM;   // elems per step round

    GLOAD16(gbase,       &lds[0][wv * 1024]);
    GLOAD16(gbase + 512, &lds[0][wv * 1024 + 512]);

    for (int t = 0; t < TSTEP; ++t) {
        const int cur = t & 1;
        __syncthreads();   // drains staging of lds[cur]; prev compute done
        if (t + 1 < TSTEP) {
            const __bf16* gnext = gbase + (size_t)(t + 1) * gstep;
            GLOAD16(gnext,       &lds[cur ^ 1][wv * 1024]);
            GLOAD16(gnext + 512, &lds[cur ^ 1][wv * 1024 + 512]);
        }

        f32x4 acc[4][2];
        const f32x4 z = {0.0f, 0.0f, 0.0f, 0.0f};
#pragma unroll
        for (int ms = 0; ms < 4; ++ms) { acc[ms][0] = z; acc[ms][1] = z; }

#pragma unroll
        for (int kb = 0; kb < 4; ++kb) {
            // B-frag row nn*16+lrow, stored chunk (kb*4+quad) ^ (lrow&7)
            const int cs = (kb * 4 + quad) ^ (lrow & 7);
            bf16x8 b0 = *(const bf16x8*)&lds[cur][(lrow * 16 + cs) * 8];
            bf16x8 b1 = *(const bf16x8*)&lds[cur][((16 + lrow) * 16 + cs) * 8];
#pragma unroll
            for (int ms = 0; ms < 4; ++ms) {
                acc[ms][0] = __builtin_amdgcn_mfma_f32_16x16x32_bf16(a[ms][kb], b0, acc[ms][0], 0, 0, 0);
                acc[ms][1] = __builtin_amdgcn_mfma_f32_16x16x32_bf16(a[ms][kb], b1, acc[ms][1], 0, 0, 0);
            }
        }
#pragma unroll
        for (int ms = 0; ms < 4; ++ms)
#pragma unroll
            for (int r = 0; r < 4; ++r)
                run[ms][r] += EXP2(acc[ms][0][r]) + EXP2(acc[ms][1][r]);
    }

    // D layout: row m = quad*4 + r (within 16-tile), col = lrow. Reduce over
    // the 16 col-lanes (lane bits 0..3), one atomic per row per wave.
#pragma unroll
    for (int ms = 0; ms < 4; ++ms)
#pragma unroll
        for (int r = 0; r < 4; ++r) {
            float v = run[ms][r];
            v += __shfl_xor(v, 1);
            v += __shfl_xor(v, 2);
            v += __shfl_xor(v, 4);
            v += __shfl_xor(v, 8);
            if (lrow == 0)
                atomicAdd(&expsum[m0 + wv * 64 + ms * 16 + quad * 4 + r], v);
        }
}

__global__ __launch_bounds__(1024) void k_fin(const float* __restrict__ expsum,
                                              const float* __restrict__ tgt,
                                              float* __restrict__ out) {
    int i = threadIdx.x;                 // 1024 threads x 4 elems = 4096
    f32x4 e = ((const f32x4*)expsum)[i];
    f32x4 g = ((const f32x4*)tgt)[i];
    float s = 0.0f;
#pragma unroll
    for (int c = 0; c < 4; ++c)
        if (i * 4 + c < NCTR) s += LN2 * __log2f(e[c]) - g[c];
#pragma unroll
    for (int off = 32; off; off >>= 1) s += __shfl_down(s, off);
    __shared__ float red[16];
    if ((i & 63) == 0) red[i >> 6] = s;
    __syncthreads();
    if (i == 0) {
        float tot = 0.0f;
#pragma unroll
        for (int w = 0; w < 16; ++w) tot += red[w];
        out[0] = tot;
    }
}

extern "C" void kernel_launch(void* const* d_in, const int* in_sizes, int n_in,
                              void* d_out, int out_size, void* d_ws, size_t ws_size,
                              hipStream_t stream) {
    const int*   tokens = (const int*)d_in[0];
    const float* emb    = (const float*)d_in[1];
    const float* W      = (const float*)d_in[2];
    float* out = (float*)d_out;
    char* ws = (char*)d_ws;
    __bf16* Wb     = (__bf16*)ws;
    __bf16* A      = (__bf16*)(ws + WS_A);
    float*  expsum = (float*)(ws + WS_EXPSUM);
    float*  tgt    = (float*)(ws + WS_TGT);

    k_setup<<<dim3(NWCONV + NCTXB), 256, 0, stream>>>(tokens, emb, W, Wb, A, tgt, expsum);
    k_gemm <<<dim3(16, SSTR), 256, 0, stream>>>(A, Wb, expsum);   // 640 blocks
    k_fin  <<<dim3(1), 1024, 0, stream>>>(expsum, tgt, out);
}